// Round 1
// baseline (2431.904 us; speedup 1.0000x reference)
//
#include <hip/hip_runtime.h>
#include <cstddef>

#define IMW   96
#define HWSZ  (IMW*IMW)       // 9216
#define CTOT  512
#define CHG   256             // channels per group
#define NBATCH 8
#define NSTEP  4

// ---------------- kernel 1: grouped 1x1 conv + channel shuffle ----------------
// h[b, 2*o+g, p] = sum_i wmix[g,o,i] * x[b, g*256+i, p]
__global__ __launch_bounds__(256) void mix_kernel(
    const float* __restrict__ x, const float* __restrict__ wmix,
    float* __restrict__ h)
{
    const int pt = blockIdx.x * 64;          // pixel tile
    const int ot = blockIdx.y * 64;          // output-channel tile (within group)
    const int b  = blockIdx.z >> 1;
    const int g  = blockIdx.z & 1;
    const float* xb = x + ((size_t)b * CTOT + (size_t)g * CHG) * HWSZ;
    const float* wg = wmix + (size_t)g * CHG * CHG;
    float* hb = h + (size_t)b * CTOT * HWSZ;

    __shared__ float Ws[16][64];   // [k][o_local]
    __shared__ float Xs[16][64];   // [k][p_local]

    const int t  = threadIdx.x;
    const int to = t >> 4;          // 0..15
    const int tp = t & 15;          // 0..15
    const int ol = t >> 2;          // 0..63  (W staging)
    const int kq = (t & 3) * 4;     // 0,4,8,12

    float acc[4][4];
    #pragma unroll
    for (int i = 0; i < 4; ++i)
        #pragma unroll
        for (int j = 0; j < 4; ++j) acc[i][j] = 0.f;

    for (int k0 = 0; k0 < CHG; k0 += 16) {
        // stage W tile, transposed to [k][o]
        float4 w4 = *(const float4*)&wg[(size_t)(ot + ol) * CHG + k0 + kq];
        Ws[kq + 0][ol] = w4.x;
        Ws[kq + 1][ol] = w4.y;
        Ws[kq + 2][ol] = w4.z;
        Ws[kq + 3][ol] = w4.w;
        // stage X tile [k][p], coalesced float4
        *(float4*)&Xs[to][tp * 4] =
            *(const float4*)&xb[(size_t)(k0 + to) * HWSZ + pt + tp * 4];
        __syncthreads();
        #pragma unroll
        for (int k = 0; k < 16; ++k) {
            float a4[4], b4[4];
            *(float4*)a4 = *(float4*)&Ws[k][to * 4];
            *(float4*)b4 = *(float4*)&Xs[k][tp * 4];
            #pragma unroll
            for (int i = 0; i < 4; ++i)
                #pragma unroll
                for (int j = 0; j < 4; ++j)
                    acc[i][j] = fmaf(a4[i], b4[j], acc[i][j]);
        }
        __syncthreads();
    }
    #pragma unroll
    for (int i = 0; i < 4; ++i) {
        const int c = 2 * (ot + to * 4 + i) + g;   // channel shuffle folded in
        float4 v = make_float4(acc[i][0], acc[i][1], acc[i][2], acc[i][3]);
        *(float4*)&hb[(size_t)c * HWSZ + pt + tp * 4] = v;
    }
}

// ------- kernel 2: per-(b,c)-plane fused dwconv3x3 + IN + affine + GELU + gate + update -------
// out may alias xcur (xcur staged through LDS) or xprev (same-thread read-before-write).
__global__ __launch_bounds__(256) void plane_kernel(
    const float* __restrict__ hmid,
    const float* xcur, const float* xprev,
    const float* __restrict__ wdw,
    const float* __restrict__ gammas, const float* __restrict__ betas,
    const float* __restrict__ alphap, int t,
    float* out)
{
    const int plane = blockIdx.x;          // b*512 + c
    const int c = plane & (CTOT - 1);
    const float* hp = hmid + (size_t)plane * HWSZ;
    const float* xp = xcur + (size_t)plane * HWSZ;
    const float* pp = xprev + (size_t)plane * HWSZ;
    float* op = out + (size_t)plane * HWSZ;

    __shared__ float sh[IMW][IMW];   // h plane
    __shared__ float sx[IMW][IMW];   // x plane

    const int tid = threadIdx.x;
    #pragma unroll
    for (int i = 0; i < 9; ++i) {               // 9216/4 = 2304 = 9*256 float4s
        ((float4*)sh)[tid + i * 256] = ((const float4*)hp)[tid + i * 256];
        ((float4*)sx)[tid + i * 256] = ((const float4*)xp)[tid + i * 256];
    }
    __syncthreads();

    float w9[9];
    #pragma unroll
    for (int i = 0; i < 9; ++i) w9[i] = wdw[c * 9 + i];

    // depthwise 3x3 (zero pad) + accumulate sums for instance norm
    float conv[36];
    float s = 0.f, s2 = 0.f;
    #pragma unroll
    for (int it = 0; it < 36; ++it) {
        const int p = tid + it * 256;
        const int y = p / IMW;
        const int xx = p - y * IMW;
        float a = 0.f;
        #pragma unroll
        for (int ky = 0; ky < 3; ++ky) {
            const int yy = y + ky - 1;
            if ((unsigned)yy < IMW) {
                #pragma unroll
                for (int kx = 0; kx < 3; ++kx) {
                    const int xx2 = xx + kx - 1;
                    if ((unsigned)xx2 < IMW)
                        a = fmaf(sh[yy][xx2], w9[ky * 3 + kx], a);
                }
            }
        }
        conv[it] = a;
        s += a;
        s2 = fmaf(a, a, s2);
    }

    // block reduction: wave shuffle then cross-wave via LDS
    #pragma unroll
    for (int off = 32; off > 0; off >>= 1) {
        s  += __shfl_down(s, off, 64);
        s2 += __shfl_down(s2, off, 64);
    }
    __shared__ float red[8];
    if ((tid & 63) == 0) { red[tid >> 6] = s; red[4 + (tid >> 6)] = s2; }
    __syncthreads();
    const float mu  = (red[0] + red[1] + red[2] + red[3]) * (1.f / HWSZ);
    const float ms  = (red[4] + red[5] + red[6] + red[7]) * (1.f / HWSZ);
    const float var = fmaxf(ms - mu * mu, 0.f);
    const float rsig = rsqrtf(var + 1e-5f);
    const float ga = gammas[t * CTOT + c];
    const float be = betas[t * CTOT + c];
    const float alpha = alphap[0];

    #pragma unroll
    for (int it = 0; it < 36; ++it) {
        const int p = tid + it * 256;
        const int y = p / IMW;
        const int xx = p - y * IMW;
        const float hn = (conv[it] - mu) * rsig * ga + be;
        const float gel = 0.5f * hn * (1.f + erff(hn * 0.70710678118654752f));
        const float xv = sx[y][xx];
        float gt = 0.f;
        #pragma unroll
        for (int dd = 0; dd < 3; ++dd) {
            const int d = 1 << dd;          // 1,2,4
            int ym = y - d;  if (ym < 0) ym += IMW;
            int xm = xx - d; if (xm < 0) xm += IMW;
            gt += fabsf(xv - sx[ym][xx]) + fabsf(xv - sx[y][xm]);
        }
        const float gate = 1.f / (1.f + expf(-gt * (1.f / 3.f)));
        const float pv = pp[p];             // store value depends on this load -> ordered
        op[p] = xv + gate * gel + alpha * (xv - pv);
    }
}

extern "C" void kernel_launch(void* const* d_in, const int* in_sizes, int n_in,
                              void* d_out, int out_size, void* d_ws, size_t ws_size,
                              hipStream_t stream) {
    const float* x0     = (const float*)d_in[0];
    const float* wmix   = (const float*)d_in[1];
    const float* wdw    = (const float*)d_in[2];
    const float* gammas = (const float*)d_in[3];
    const float* betas  = (const float*)d_in[4];
    const float* alphap = (const float*)d_in[5];

    const size_t NELEM = (size_t)NBATCH * CTOT * HWSZ;   // 37,748,736
    float* D  = (float*)d_out;          // holds x1, then x3, then x4 (final)
    float* S  = (float*)d_ws;           // holds x2
    float* Hb = (float*)d_ws + NELEM;   // mix output, reused each step

    dim3 mgrid(HWSZ / 64, CHG / 64, NBATCH * 2);   // (144, 4, 16)
    const int pgrid = NBATCH * CTOT;               // 4096

    // t=0: cur=x0 prev=x0 -> D
    mix_kernel<<<mgrid, 256, 0, stream>>>(x0, wmix, Hb);
    plane_kernel<<<pgrid, 256, 0, stream>>>(Hb, x0, x0, wdw, gammas, betas, alphap, 0, D);
    // t=1: cur=D prev=x0 -> S
    mix_kernel<<<mgrid, 256, 0, stream>>>(D, wmix, Hb);
    plane_kernel<<<pgrid, 256, 0, stream>>>(Hb, D, x0, wdw, gammas, betas, alphap, 1, S);
    // t=2: cur=S prev=D -> D (in-place over prev: same-thread read-before-write)
    mix_kernel<<<mgrid, 256, 0, stream>>>(S, wmix, Hb);
    plane_kernel<<<pgrid, 256, 0, stream>>>(Hb, S, D, wdw, gammas, betas, alphap, 2, D);
    // t=3: cur=D prev=S -> D (in-place over cur: cur staged via LDS first)
    mix_kernel<<<mgrid, 256, 0, stream>>>(D, wmix, Hb);
    plane_kernel<<<pgrid, 256, 0, stream>>>(Hb, D, S, wdw, gammas, betas, alphap, 3, D);
}

// Round 2
// 934.727 us; speedup vs baseline: 2.6017x; 2.6017x over previous
//
#include <hip/hip_runtime.h>
#include <cstddef>

#define IMW   96
#define HWSZ  (IMW*IMW)       // 9216
#define CTOT  512
#define CHG   256             // channels per group
#define NBATCH 8

typedef short bf16x8 __attribute__((ext_vector_type(8)));
typedef float f32x4  __attribute__((ext_vector_type(4)));

__device__ __forceinline__ ushort f2bf(float f) {
    union { float f; unsigned u; } v; v.f = f;
    unsigned r = v.u + 0x7fffu + ((v.u >> 16) & 1u);   // RNE
    return (ushort)(r >> 16);
}
__device__ __forceinline__ float bf2f(ushort u) {
    union { unsigned u; float f; } v; v.u = ((unsigned)u) << 16;
    return v.f;
}

// ---- tiny: convert w_mix (2x256x256 fp32) to bf16 once per launch ----
__global__ __launch_bounds__(256) void wconv_kernel(const float* __restrict__ w,
                                                    ushort* __restrict__ wbf) {
    const int i = blockIdx.x * 256 + threadIdx.x;
    wbf[i] = f2bf(w[i]);
}

// ---------------- kernel 1: grouped 1x1 conv + shuffle, bf16 MFMA ----------------
// H[o,p] = sum_k W[g,o,k] * X[b,g*256+k,p]; stored to hb[2o+g][p] as bf16.
// Block: all 256 o-rows (4 waves x 64) x 64-pixel tile. X^T staged in LDS (fp32->bf16).
#define XT_LD 280   // ushort stride: 560 B = 140 dwords, 140%32=12 -> 2-way banks only

__global__ __launch_bounds__(256, 3) void mix_mfma(
    const float* __restrict__ x, const ushort* __restrict__ wbf,
    ushort* __restrict__ h)
{
    const int pt = blockIdx.x * 64;
    const int b  = blockIdx.y >> 1, g = blockIdx.y & 1;
    const float*  xb = x + ((size_t)b * CTOT + (size_t)g * CHG) * HWSZ;
    const ushort* wg = wbf + (size_t)g * CHG * CHG;
    ushort* hb = h + (size_t)b * CTOT * HWSZ;

    __shared__ ushort Xt[64][XT_LD];   // [pixel][k], 35 KB

    const int t  = threadIdx.x;
    const int tq = t & 15;             // pixel quad
    const int tk = t >> 4;             // k-pair selector

    #pragma unroll
    for (int it = 0; it < 8; ++it) {   // covers all even k
        const int k = 32 * it + 2 * tk;
        float4 a0 = *(const float4*)&xb[(size_t)k       * HWSZ + pt + 4 * tq];
        float4 a1 = *(const float4*)&xb[(size_t)(k + 1) * HWSZ + pt + 4 * tq];
        unsigned u0 = (unsigned)f2bf(a0.x) | ((unsigned)f2bf(a1.x) << 16);
        unsigned u1 = (unsigned)f2bf(a0.y) | ((unsigned)f2bf(a1.y) << 16);
        unsigned u2 = (unsigned)f2bf(a0.z) | ((unsigned)f2bf(a1.z) << 16);
        unsigned u3 = (unsigned)f2bf(a0.w) | ((unsigned)f2bf(a1.w) << 16);
        *(unsigned*)&Xt[4 * tq + 0][k] = u0;
        *(unsigned*)&Xt[4 * tq + 1][k] = u1;
        *(unsigned*)&Xt[4 * tq + 2][k] = u2;
        *(unsigned*)&Xt[4 * tq + 3][k] = u3;
    }
    __syncthreads();

    const int wv  = t >> 6;            // wave -> 64 o-rows
    const int ln  = t & 63;
    const int row = ln & 15;           // A row / B col / D col
    const int kb  = ln >> 4;           // k-block of 8

    f32x4 acc[4][4];
    #pragma unroll
    for (int m = 0; m < 4; ++m)
        #pragma unroll
        for (int n = 0; n < 4; ++n)
            acc[m][n] = (f32x4){0.f, 0.f, 0.f, 0.f};

    #pragma unroll
    for (int ks = 0; ks < 8; ++ks) {
        bf16x8 A[4], Bf[4];
        #pragma unroll
        for (int m = 0; m < 4; ++m)
            A[m] = *(const bf16x8*)&wg[(size_t)(64 * wv + 16 * m + row) * CHG + 32 * ks + 8 * kb];
        #pragma unroll
        for (int n = 0; n < 4; ++n)
            Bf[n] = *(const bf16x8*)&Xt[16 * n + row][32 * ks + 8 * kb];
        #pragma unroll
        for (int m = 0; m < 4; ++m)
            #pragma unroll
            for (int n = 0; n < 4; ++n)
                acc[m][n] = __builtin_amdgcn_mfma_f32_16x16x32_bf16(A[m], Bf[n], acc[m][n], 0, 0, 0);
    }

    #pragma unroll
    for (int m = 0; m < 4; ++m) {
        #pragma unroll
        for (int n = 0; n < 4; ++n) {
            const int p = pt + 16 * n + row;
            #pragma unroll
            for (int j = 0; j < 4; ++j) {
                const int o = 64 * wv + 16 * m + 4 * kb + j;
                hb[(size_t)(2 * o + g) * HWSZ + p] = f2bf(acc[m][n][j]);   // channel shuffle folded
            }
        }
    }
}

// ------- kernel 2: fused dwconv3x3 + IN + affine + GELU + gate + update -------
// 512 threads per (b,c) plane; h and x staged bf16 in LDS; x/prev read fp32 from global.
__global__ __launch_bounds__(512, 4) void plane_kernel(
    const ushort* __restrict__ hmid,
    const float* xcur, const float* xprev,
    const float* __restrict__ wdw,
    const float* __restrict__ gammas, const float* __restrict__ betas,
    const float* __restrict__ alphap, int t,
    float* out)
{
    const int plane = blockIdx.x;          // b*512 + c
    const int c = plane & (CTOT - 1);
    const ushort* hp = hmid + (size_t)plane * HWSZ;
    const float*  xp = xcur + (size_t)plane * HWSZ;
    const float*  pp = xprev + (size_t)plane * HWSZ;
    float* op = out + (size_t)plane * HWSZ;

    __shared__ ushort sh[IMW][IMW];   // 18 KB bf16 h plane
    __shared__ ushort sx[IMW][IMW];   // 18 KB bf16 x plane (gate neighbors only)
    __shared__ float  red[16];

    const int tid = threadIdx.x;
    for (int i = tid; i < 1152; i += 512)                  // 18 KB = 1152 x 16 B
        ((uint4*)sh)[i] = ((const uint4*)hp)[i];
    for (int i = tid; i < 2304; i += 512) {                // fp32 -> bf16, 8 B writes
        float4 v = ((const float4*)xp)[i];
        ushort4 u4;
        u4.x = f2bf(v.x); u4.y = f2bf(v.y); u4.z = f2bf(v.z); u4.w = f2bf(v.w);
        ((ushort4*)sx)[i] = u4;
    }
    __syncthreads();

    float w9[9];
    #pragma unroll
    for (int i = 0; i < 9; ++i) w9[i] = wdw[c * 9 + i];

    const int y0 = tid / IMW;          // one-time div
    const int x0 = tid - y0 * IMW;

    // pass 1: depthwise conv + moment sums (p = tid + it*512; 512 = 5*96+32)
    float conv[18];
    float s = 0.f, s2 = 0.f;
    {
        int y = y0, xx = x0;
        #pragma unroll
        for (int it = 0; it < 18; ++it) {
            float a = 0.f;
            #pragma unroll
            for (int ky = 0; ky < 3; ++ky) {
                const int yy = y + ky - 1;
                if ((unsigned)yy < IMW) {
                    #pragma unroll
                    for (int kx = 0; kx < 3; ++kx) {
                        const int x2 = xx + kx - 1;
                        if ((unsigned)x2 < IMW)
                            a = fmaf(bf2f(sh[yy][x2]), w9[ky * 3 + kx], a);
                    }
                }
            }
            conv[it] = a;
            s += a; s2 = fmaf(a, a, s2);
            xx += 32; y += 5; if (xx >= IMW) { xx -= IMW; y += 1; }
        }
    }

    #pragma unroll
    for (int off = 32; off; off >>= 1) {
        s  += __shfl_down(s, off, 64);
        s2 += __shfl_down(s2, off, 64);
    }
    if ((tid & 63) == 0) { red[tid >> 6] = s; red[8 + (tid >> 6)] = s2; }
    __syncthreads();
    float ssum = 0.f, s2sum = 0.f;
    #pragma unroll
    for (int i = 0; i < 8; ++i) { ssum += red[i]; s2sum += red[8 + i]; }
    const float mu   = ssum * (1.f / HWSZ);
    const float var  = fmaxf(s2sum * (1.f / HWSZ) - mu * mu, 0.f);
    const float rsig = rsqrtf(var + 1e-5f);
    const float ga = gammas[t * CTOT + c] * rsig;
    const float be = betas[t * CTOT + c];
    const float alpha = alphap[0];

    // pass 2: affine + GELU(tanh approx) + gate + residual update
    {
        int y = y0, xx = x0;
        #pragma unroll
        for (int it = 0; it < 18; ++it) {
            const int p = tid + it * 512;
            const float hn = (conv[it] - mu) * ga + be;
            const float z  = 0.7978845608f * fmaf(0.044715f * hn * hn, hn, hn);
            const float e2 = __expf(2.f * z);
            const float th = 1.f - 2.f * __builtin_amdgcn_rcpf(e2 + 1.f);
            const float gel = 0.5f * hn * (1.f + th);
            const float xv = xp[p];                      // fp32 state
            float gt = 0.f;
            #pragma unroll
            for (int dd = 0; dd < 3; ++dd) {
                const int d = 1 << dd;
                int ym = y - d;  ym += (ym < 0) ? IMW : 0;
                int xm = xx - d; xm += (xm < 0) ? IMW : 0;
                gt += fabsf(xv - bf2f(sx[ym][xx])) + fabsf(xv - bf2f(sx[y][xm]));
            }
            const float eg   = __expf(gt * (-1.f / 3.f));
            const float gate = __builtin_amdgcn_rcpf(1.f + eg);
            const float pv = pp[p];                      // read-before-write, same thread
            op[p] = fmaf(alpha, xv - pv, fmaf(gate, gel, xv));
            xx += 32; y += 5; if (xx >= IMW) { xx -= IMW; y += 1; }
        }
    }
}

extern "C" void kernel_launch(void* const* d_in, const int* in_sizes, int n_in,
                              void* d_out, int out_size, void* d_ws, size_t ws_size,
                              hipStream_t stream) {
    const float* x0     = (const float*)d_in[0];
    const float* wmix   = (const float*)d_in[1];
    const float* wdw    = (const float*)d_in[2];
    const float* gammas = (const float*)d_in[3];
    const float* betas  = (const float*)d_in[4];
    const float* alphap = (const float*)d_in[5];

    const size_t NELEM = (size_t)NBATCH * CTOT * HWSZ;   // 37,748,736
    float*  D   = (float*)d_out;                          // x1, x3, x4(final)
    char*   ws  = (char*)d_ws;
    float*  S   = (float*)ws;                             // x2 (fp32)
    ushort* Hb  = (ushort*)(ws + NELEM * 4);              // mix output, bf16
    ushort* Wbf = (ushort*)(ws + NELEM * 4 + NELEM * 2);  // w_mix bf16 (256 KB)

    wconv_kernel<<<512, 256, 0, stream>>>(wmix, Wbf);

    dim3 mgrid(HWSZ / 64, NBATCH * 2);   // (144, 16)
    const int pgrid = NBATCH * CTOT;     // 4096

    // t=0: cur=x0 prev=x0 -> D
    mix_mfma<<<mgrid, 256, 0, stream>>>(x0, Wbf, Hb);
    plane_kernel<<<pgrid, 512, 0, stream>>>(Hb, x0, x0, wdw, gammas, betas, alphap, 0, D);
    // t=1: cur=D prev=x0 -> S
    mix_mfma<<<mgrid, 256, 0, stream>>>(D, Wbf, Hb);
    plane_kernel<<<pgrid, 512, 0, stream>>>(Hb, D, x0, wdw, gammas, betas, alphap, 1, S);
    // t=2: cur=S prev=D -> D (in-place over prev: same-thread read-before-write)
    mix_mfma<<<mgrid, 256, 0, stream>>>(S, Wbf, Hb);
    plane_kernel<<<pgrid, 512, 0, stream>>>(Hb, S, D, wdw, gammas, betas, alphap, 2, D);
    // t=3: cur=D prev=S -> D (cur staged via LDS + same-thread ordering)
    mix_mfma<<<mgrid, 256, 0, stream>>>(D, Wbf, Hb);
    plane_kernel<<<pgrid, 512, 0, stream>>>(Hb, D, S, wdw, gammas, betas, alphap, 3, D);
}

// Round 3
// 778.789 us; speedup vs baseline: 3.1227x; 1.2002x over previous
//
#include <hip/hip_runtime.h>
#include <cstddef>

#define IMW   96
#define HWSZ  (IMW*IMW)       // 9216
#define CTOT  512
#define CHG   256             // channels per group
#define NBATCH 8
#define ROWP  104             // padded LDS row stride (ushorts): 208 B -> banks spread

typedef short  bf16x8  __attribute__((ext_vector_type(8)));
typedef float  f32x4   __attribute__((ext_vector_type(4)));
typedef unsigned short ushort8v __attribute__((ext_vector_type(8)));

__device__ __forceinline__ ushort f2bf(float f) {
    union { float f; unsigned u; } v; v.f = f;
    unsigned r = v.u + 0x7fffu + ((v.u >> 16) & 1u);   // RNE
    return (ushort)(r >> 16);
}
__device__ __forceinline__ float bf2f(ushort u) {
    union { unsigned u; float f; } v; v.u = ((unsigned)u) << 16;
    return v.f;
}

// ---- tiny: convert w_mix (2x256x256 fp32) to bf16 once per launch ----
__global__ __launch_bounds__(256) void wconv_kernel(const float* __restrict__ w,
                                                    ushort* __restrict__ wbf) {
    const int i = blockIdx.x * 256 + threadIdx.x;
    wbf[i] = f2bf(w[i]);
}

// ---------------- kernel 1: grouped 1x1 conv + shuffle, bf16 MFMA ----------------
// D = X^T x W^T -> D[pixel][o]; 4 consecutive pixels per acc reg -> ushort4 stores.
#define XT_LD 280   // ushort stride: 560 B = 140 dwords, 140%32=12 -> 2-way banks only

__global__ __launch_bounds__(256, 3) void mix_mfma(
    const float* __restrict__ x, const ushort* __restrict__ wbf,
    ushort* __restrict__ h)
{
    const int pt = blockIdx.x * 64;
    const int b  = blockIdx.y >> 1, g = blockIdx.y & 1;
    const float*  xb = x + ((size_t)b * CTOT + (size_t)g * CHG) * HWSZ;
    const ushort* wg = wbf + (size_t)g * CHG * CHG;
    ushort* hb = h + (size_t)b * CTOT * HWSZ;

    __shared__ ushort Xt[64][XT_LD];   // [pixel][k], 35 KB

    const int t  = threadIdx.x;
    const int tq = t & 15;             // pixel quad
    const int tk = t >> 4;             // k-pair selector

    #pragma unroll
    for (int it = 0; it < 8; ++it) {   // covers all k
        const int k = 32 * it + 2 * tk;
        float4 a0 = *(const float4*)&xb[(size_t)k       * HWSZ + pt + 4 * tq];
        float4 a1 = *(const float4*)&xb[(size_t)(k + 1) * HWSZ + pt + 4 * tq];
        *(unsigned*)&Xt[4 * tq + 0][k] = (unsigned)f2bf(a0.x) | ((unsigned)f2bf(a1.x) << 16);
        *(unsigned*)&Xt[4 * tq + 1][k] = (unsigned)f2bf(a0.y) | ((unsigned)f2bf(a1.y) << 16);
        *(unsigned*)&Xt[4 * tq + 2][k] = (unsigned)f2bf(a0.z) | ((unsigned)f2bf(a1.z) << 16);
        *(unsigned*)&Xt[4 * tq + 3][k] = (unsigned)f2bf(a0.w) | ((unsigned)f2bf(a1.w) << 16);
    }
    __syncthreads();

    const int wv  = t >> 6;            // wave -> 64 o-channels
    const int ln  = t & 63;
    const int row = ln & 15;
    const int kb  = ln >> 4;

    f32x4 acc[4][4];
    #pragma unroll
    for (int m = 0; m < 4; ++m)
        #pragma unroll
        for (int n = 0; n < 4; ++n)
            acc[m][n] = (f32x4){0.f, 0.f, 0.f, 0.f};

    #pragma unroll
    for (int ks = 0; ks < 8; ++ks) {
        bf16x8 Xf[4], Wf[4];
        #pragma unroll
        for (int m = 0; m < 4; ++m)    // A operand: X^T[pixel=16m+row][k]
            Xf[m] = *(const bf16x8*)&Xt[16 * m + row][32 * ks + 8 * kb];
        #pragma unroll
        for (int n = 0; n < 4; ++n)    // B operand: W^T[k][o=64wv+16n+row]
            Wf[n] = *(const bf16x8*)&wg[(size_t)(64 * wv + 16 * n + row) * CHG + 32 * ks + 8 * kb];
        #pragma unroll
        for (int m = 0; m < 4; ++m)
            #pragma unroll
            for (int n = 0; n < 4; ++n)
                acc[m][n] = __builtin_amdgcn_mfma_f32_16x16x32_bf16(Xf[m], Wf[n], acc[m][n], 0, 0, 0);
    }

    // D: col(lane&15)=o-local, row(4*kb+j)=pixel-local -> 4 consecutive px per reg set
    #pragma unroll
    for (int m = 0; m < 4; ++m) {
        #pragma unroll
        for (int n = 0; n < 4; ++n) {
            const int o = 64 * wv + 16 * n + row;
            const int c = 2 * o + g;                       // channel shuffle folded
            const int p = pt + 16 * m + 4 * kb;
            ushort4 u;
            u.x = f2bf(acc[m][n][0]); u.y = f2bf(acc[m][n][1]);
            u.z = f2bf(acc[m][n][2]); u.w = f2bf(acc[m][n][3]);
            *(ushort4*)&hb[(size_t)c * HWSZ + p] = u;
        }
    }
}

// ------- kernel 2: fused dwconv3x3 + IN + affine + GELU + gate + update -------
// 576 threads: 96 rows x 6 segments x 16 px. Vector LDS reads from padded rows.
__global__ __launch_bounds__(576, 5) void plane_kernel(
    const ushort* __restrict__ hmid,
    const float* xcur, const float* xprev,
    const float* __restrict__ wdw,
    const float* __restrict__ gammas, const float* __restrict__ betas,
    const float* __restrict__ alphap, int t,
    float* out)
{
    const int plane = blockIdx.x;          // b*512 + c
    const int c = plane & (CTOT - 1);
    const ushort* hp = hmid + (size_t)plane * HWSZ;
    const float*  xp = xcur + (size_t)plane * HWSZ;
    const float*  pp = xprev + (size_t)plane * HWSZ;
    float* op = out + (size_t)plane * HWSZ;

    __shared__ ushort sh[IMW * ROWP];   // h plane bf16, padded rows (~20 KB)
    __shared__ ushort sx[IMW * ROWP];   // x plane bf16, padded rows (~20 KB)
    __shared__ float  red[32];

    const int tid = threadIdx.x;
    const int r   = tid / 6;            // row 0..95
    const int s6  = tid - r * 6;        // segment 0..5
    const int x0  = s6 * 16;

    // stage h: 2 x 16B per thread
    {
        const uint4* src = (const uint4*)(hp + (size_t)r * IMW);
        uint4* dst = (uint4*)(sh + r * ROWP);
        dst[2 * s6]     = src[2 * s6];
        dst[2 * s6 + 1] = src[2 * s6 + 1];
    }
    // stage x: fp32 -> bf16
    {
        const float4* src = (const float4*)(xp + (size_t)r * IMW);
        ushort4* dst = (ushort4*)(sx + r * ROWP);
        #pragma unroll
        for (int q = 0; q < 4; ++q) {
            float4 v = src[4 * s6 + q];
            ushort4 u;
            u.x = f2bf(v.x); u.y = f2bf(v.y); u.z = f2bf(v.z); u.w = f2bf(v.w);
            dst[4 * s6 + q] = u;
        }
    }
    __syncthreads();

    float w9[9];
    #pragma unroll
    for (int i = 0; i < 9; ++i) w9[i] = wdw[c * 9 + i];

    // pass 1: depthwise 3x3 from register row windows
    float conv[16];
    #pragma unroll
    for (int i = 0; i < 16; ++i) conv[i] = 0.f;
    #pragma unroll
    for (int ky = 0; ky < 3; ++ky) {
        const int yy = r + ky - 1;
        if ((unsigned)yy < IMW) {
            const ushort* rp = sh + yy * ROWP + x0;
            float f[18];                       // f[j] = row[x0-1+j]
            ushort8v a = *(const ushort8v*)rp;
            ushort8v bq = *(const ushort8v*)(rp + 8);
            f[0]  = (s6 > 0) ? bf2f(rp[-1]) : 0.f;
            f[17] = (s6 < 5) ? bf2f(rp[16]) : 0.f;
            #pragma unroll
            for (int j = 0; j < 8; ++j) { f[1 + j] = bf2f(a[j]); f[9 + j] = bf2f(bq[j]); }
            const float w0 = w9[3 * ky], w1 = w9[3 * ky + 1], w2 = w9[3 * ky + 2];
            #pragma unroll
            for (int i = 0; i < 16; ++i)
                conv[i] = fmaf(w0, f[i], fmaf(w1, f[i + 1], fmaf(w2, f[i + 2], conv[i])));
        }
    }

    float s = 0.f, s2 = 0.f;
    #pragma unroll
    for (int i = 0; i < 16; ++i) { s += conv[i]; s2 = fmaf(conv[i], conv[i], s2); }
    #pragma unroll
    for (int off = 32; off; off >>= 1) {
        s  += __shfl_down(s, off, 64);
        s2 += __shfl_down(s2, off, 64);
    }
    const int wv = tid >> 6;           // 0..8
    if ((tid & 63) == 0) { red[wv] = s; red[16 + wv] = s2; }
    __syncthreads();
    float ssum = 0.f, s2sum = 0.f;
    #pragma unroll
    for (int i = 0; i < 9; ++i) { ssum += red[i]; s2sum += red[16 + i]; }
    const float mu   = ssum * (1.f / HWSZ);
    const float var  = fmaxf(s2sum * (1.f / HWSZ) - mu * mu, 0.f);
    const float rsig = rsqrtf(var + 1e-5f);
    const float ga = gammas[t * CTOT + c] * rsig;
    const float be = betas[t * CTOT + c];
    const float alpha = alphap[0];

    // pass 2: gate + GELU + residual update, two 8-px halves
    #pragma unroll
    for (int half = 0; half < 2; ++half) {
        const int xbx = x0 + 8 * half;
        const int gbase = r * IMW + xbx;

        float xv[8];
        {
            float4 v0 = *(const float4*)(xp + gbase);
            float4 v1 = *(const float4*)(xp + gbase + 4);
            xv[0] = v0.x; xv[1] = v0.y; xv[2] = v0.z; xv[3] = v0.w;
            xv[4] = v1.x; xv[5] = v1.y; xv[6] = v1.z; xv[7] = v1.w;
        }
        float pv[8];
        {
            float4 v0 = *(const float4*)(pp + gbase);
            float4 v1 = *(const float4*)(pp + gbase + 4);
            pv[0] = v0.x; pv[1] = v0.y; pv[2] = v0.z; pv[3] = v0.w;
            pv[4] = v1.x; pv[5] = v1.y; pv[6] = v1.z; pv[7] = v1.w;
        }
        // horizontal window wnd[j] = x_row[(xbx-8+j) mod 96]  (wrap only hits at xbx==0)
        float wnd[16];
        {
            const int lx = (xbx == 0) ? (IMW - 8) : (xbx - 8);
            ushort8v h0 = *(const ushort8v*)(sx + r * ROWP + lx);
            ushort8v h1 = *(const ushort8v*)(sx + r * ROWP + xbx);
            #pragma unroll
            for (int j = 0; j < 8; ++j) { wnd[j] = bf2f(h0[j]); wnd[8 + j] = bf2f(h1[j]); }
        }
        float gt[8];
        #pragma unroll
        for (int i = 0; i < 8; ++i) gt[i] = 0.f;
        #pragma unroll
        for (int dd = 0; dd < 3; ++dd) {
            const int d = 1 << dd;
            int ym = r - d; if (ym < 0) ym += IMW;
            ushort8v vr = *(const ushort8v*)(sx + ym * ROWP + xbx);
            #pragma unroll
            for (int i = 0; i < 8; ++i)
                gt[i] += fabsf(xv[i] - bf2f(vr[i])) + fabsf(xv[i] - wnd[8 + i - d]);
        }
        float o8[8];
        #pragma unroll
        for (int i = 0; i < 8; ++i) {
            const float hn  = fmaf(conv[8 * half + i] - mu, ga, be);
            const float z   = 0.7978845608f * fmaf(0.044715f * hn * hn, hn, hn);
            const float e2  = __expf(2.f * z);
            const float th  = 1.f - 2.f * __builtin_amdgcn_rcpf(e2 + 1.f);
            const float gel = 0.5f * hn * (1.f + th);
            const float eg   = __expf(gt[i] * (-1.f / 3.f));
            const float gate = __builtin_amdgcn_rcpf(1.f + eg);
            o8[i] = fmaf(alpha, xv[i] - pv[i], fmaf(gate, gel, xv[i]));
        }
        *(float4*)(op + gbase)     = make_float4(o8[0], o8[1], o8[2], o8[3]);
        *(float4*)(op + gbase + 4) = make_float4(o8[4], o8[5], o8[6], o8[7]);
    }
}

extern "C" void kernel_launch(void* const* d_in, const int* in_sizes, int n_in,
                              void* d_out, int out_size, void* d_ws, size_t ws_size,
                              hipStream_t stream) {
    const float* x0     = (const float*)d_in[0];
    const float* wmix   = (const float*)d_in[1];
    const float* wdw    = (const float*)d_in[2];
    const float* gammas = (const float*)d_in[3];
    const float* betas  = (const float*)d_in[4];
    const float* alphap = (const float*)d_in[5];

    const size_t NELEM = (size_t)NBATCH * CTOT * HWSZ;   // 37,748,736
    float*  D   = (float*)d_out;                          // x1, x3, x4(final)
    char*   ws  = (char*)d_ws;
    float*  S   = (float*)ws;                             // x2 (fp32)
    ushort* Hb  = (ushort*)(ws + NELEM * 4);              // mix output, bf16
    ushort* Wbf = (ushort*)(ws + NELEM * 4 + NELEM * 2);  // w_mix bf16 (256 KB)

    wconv_kernel<<<512, 256, 0, stream>>>(wmix, Wbf);

    dim3 mgrid(HWSZ / 64, NBATCH * 2);   // (144, 16)
    const int pgrid = NBATCH * CTOT;     // 4096

    // t=0: cur=x0 prev=x0 -> D
    mix_mfma<<<mgrid, 256, 0, stream>>>(x0, Wbf, Hb);
    plane_kernel<<<pgrid, 576, 0, stream>>>(Hb, x0, x0, wdw, gammas, betas, alphap, 0, D);
    // t=1: cur=D prev=x0 -> S
    mix_mfma<<<mgrid, 256, 0, stream>>>(D, Wbf, Hb);
    plane_kernel<<<pgrid, 576, 0, stream>>>(Hb, D, x0, wdw, gammas, betas, alphap, 1, S);
    // t=2: cur=S prev=D -> D (in-place over prev: same-thread read-before-write)
    mix_mfma<<<mgrid, 256, 0, stream>>>(S, Wbf, Hb);
    plane_kernel<<<pgrid, 576, 0, stream>>>(Hb, S, D, wdw, gammas, betas, alphap, 2, D);
    // t=3: cur=D prev=S -> D (cur staged via LDS + same-thread ordering)
    mix_mfma<<<mgrid, 256, 0, stream>>>(D, Wbf, Hb);
    plane_kernel<<<pgrid, 576, 0, stream>>>(Hb, D, S, wdw, gammas, betas, alphap, 3, D);
}